// Round 16
// baseline (122.058 us; speedup 1.0000x reference)
//
#include <hip/hip_runtime.h>

// SymmetricContraction as ONE bf16 MFMA GEMM (32x32x16), SPLIT-K x2:
//   t[ch, k] = sum_m P[ch, m] * Uemb[m, k], 976 embedded rows, 61 K=16 chunks:
//     m   0..815 : triples a<=b<=c   P = xa*xb*xc, cols 0..22  = U3sym
//     m 816..951 : pairs  a<=b       P = xa*xb,    cols 23..26 = U2sym
//     m 952..967 : singles w         P = xw,       col  27     = U1
//     m 968..975 : zero pad
// Single-bf16 U (R14-verified: absmax 4.0 vs threshold 16.64).
//
// Round-15 post-mortem (absmax 268): chunk_body picks the B-register by CHUNK
// PARITY (even CH -> nb0, odd -> nb1), but wave 1 starts at ODD CH=31 and its
// prologue loaded nb0=chunk31, nb1=chunk32 -> every wave-1 chunk consumed its
// NEIGHBOR'S U (B-stream shifted by one chunk). Wave 0 (even start) was fine.
// Fix: wave-1 prologue loads BY PARITY: nb1 = chunk 31 (odd), nb0 = chunk 32
// (even). Everything else identical to R15.
// Rationale (R14 post-mortem): per-wave 61-chunk serial chain under a
// ~6-wave/CU residency cap -> halve the chain per wave, constant total work.

#define B_   1024
#define C_   256
#define L_   16
#define E_   10
#define K3_  23
#define K2_  4

#define NM3  816
#define NM2  136
#define MTOT 992
#define NCH2 61      // K=16 chunks 0..60
#define SPLIT 31     // wave0: [0,31), wave1: [31,61)
#define STSTR 68     // sT row stride in floats

using f32x4   = __attribute__((ext_vector_type(4))) float;
using f32x16  = __attribute__((ext_vector_type(16))) float;
using short8v = __attribute__((ext_vector_type(8))) short;

__device__ __host__ __forceinline__ constexpr int tri_(int n) { return n * (n + 1) / 2; }
__device__ __host__ __forceinline__ constexpr int tet_(int n) { return n * (n + 1) * (n + 2) / 6; }

// ---- compile-time multiset table: a<=b<=c triples, then pairs (c=16),
// singles (b=c=16), pad (a=17).
struct MTab { unsigned char a[MTOT], b[MTOT], c[MTOT]; };
constexpr MTab mkMT() {
  MTab t = {};
  int m = 0;
  for (int a = 0; a < 16; a++)
    for (int b = a; b < 16; b++)
      for (int c = b; c < 16; c++) { t.a[m] = a; t.b[m] = b; t.c[m] = c; ++m; }
  for (int a = 0; a < 16; a++)
    for (int b = a; b < 16; b++) { t.a[m] = a; t.b[m] = b; t.c[m] = 16; ++m; }
  for (int a = 0; a < 16; a++) { t.a[m] = a; t.b[m] = 16; t.c[m] = 16; ++m; }
  while (m < MTOT) { t.a[m] = 17; t.b[m] = 17; t.c[m] = 17; ++m; }
  return t;
}
constexpr MTab MT = mkMT();

// ---------------- prep: U rows -> single-bf16 B-frags (verbatim R14) ------
__global__ void prep_kernel(const float* __restrict__ U3, const float* __restrict__ U2,
                            const float* __restrict__ U1, unsigned short* __restrict__ wsFrag) {
  __shared__ float sRow[16][36];
  const int ch = blockIdx.x;       // 0..60
  const int tid = threadIdx.x;     // 0..63
  if (tid < 16) {
    const int m = ch * 16 + tid;
    for (int i = 0; i < 36; i++) sRow[tid][i] = 0.f;
    if (m < NM3) {
      int ia = 0;
      while (tet_(16) - tet_(16 - (ia + 1)) <= m) ia++;
      int rem = m - (tet_(16) - tet_(16 - ia));
      int ib = ia;
      while (tri_(16 - ia) - tri_(16 - (ib + 1)) <= rem) ib++;
      int ic = ib + (rem - (tri_(16 - ia) - tri_(16 - ib)));
      int pw[6] = {ia, ia, ib, ib, ic, ic};
      int pv[6] = {ib, ic, ia, ic, ia, ib};
      int pi[6] = {ic, ib, ic, ia, ib, ia};
      bool use[6];
      for (int p = 0; p < 6; p++) {
        bool dup = false;
        for (int q = 0; q < p; q++)
          dup = dup || (pw[p] == pw[q] && pv[p] == pv[q] && pi[p] == pi[q]);
        use[p] = !dup;
      }
      for (int k = 0; k < K3_; k++) {
        float s = 0.f;
        for (int p = 0; p < 6; p++)
          if (use[p]) s += U3[((pw[p] * L_ + pv[p]) * L_ + pi[p]) * K3_ + k];
        sRow[tid][k] = s;
      }
    } else if (m < NM3 + NM2) {
      const int pidx = m - NM3;
      int ia = 0;
      while (136 - tri_(16 - (ia + 1)) <= pidx) ia++;
      int ib = ia + (pidx - (136 - tri_(16 - ia)));
      for (int k2 = 0; k2 < K2_; k2++) {
        float s = U2[(ia * L_ + ib) * K2_ + k2];
        if (ia != ib) s += U2[(ib * L_ + ia) * K2_ + k2];
        sRow[tid][23 + k2] = s;
      }
    } else if (m < NM3 + NM2 + L_) {
      sRow[tid][27] = U1[m - NM3 - NM2];
    }
  }
  __syncthreads();
  {
    const int lane = tid;
    unsigned short v16[8];
    for (int j = 0; j < 8; j++) {
      float v = sRow[(lane >> 5) * 8 + j][lane & 31];
      unsigned vb = __float_as_uint(v) + 0x8000u;   // bf16 round-half-up
      v16[j] = (unsigned short)(vb >> 16);
    }
    unsigned* dst = (unsigned*)(wsFrag + ((size_t)ch * 64 + lane) * 8);
    for (int p = 0; p < 4; p++)
      dst[p] = (unsigned)v16[2 * p] | ((unsigned)v16[2 * p + 1] << 16);
  }
}

// ---------------- permlane32_swap: vdst.hi <-> vsrc.lo (both updated) ------
__device__ __forceinline__ void lane32_swap(unsigned& a, unsigned& b) {
#if defined(__has_builtin) && __has_builtin(__builtin_amdgcn_permlane32_swap)
  auto r = __builtin_amdgcn_permlane32_swap((int)a, (int)b, false, false);
  a = (unsigned)r[0];
  b = (unsigned)r[1];
#else
  asm volatile("v_permlane32_swap_b32 %0, %1" : "+v"(a), "+v"(b));
#endif
}

// P(m), compile-time specialized (constexpr MT). M is a template constant.
template <int M>
__device__ __forceinline__ float pval(const float (&XX)[16]) {
  if constexpr (MT.a[M] == 17) return 0.f;
  else if constexpr (MT.b[M] == 16) return XX[MT.a[M]];
  else if constexpr (MT.c[M] == 16) return XX[MT.a[M]] * XX[MT.b[M]];
  else return XX[MT.a[M]] * XX[MT.b[M]] * XX[MT.c[M]];
}

template <int CH, int I>
__device__ __forceinline__ void pk_pair(const float (&XX)[16],
                                        unsigned& o0, unsigned& o1) {
  {
    float p0 = pval<CH * 16 + 2 * I>(XX);
    float p1 = pval<CH * 16 + 2 * I + 1>(XX);
    asm("v_cvt_pk_bf16_f32 %0, %1, %2" : "=v"(o0) : "v"(p0), "v"(p1));
  }
  {
    float p0 = pval<CH * 16 + 8 + 2 * I>(XX);
    float p1 = pval<CH * 16 + 8 + 2 * I + 1>(XX);
    asm("v_cvt_pk_bf16_f32 %0, %1, %2" : "=v"(o1) : "v"(p0), "v"(p1));
  }
  // A0 = {lo: own slice0, hi: partner slice1}; A1 = {lo: partner s0, hi: own s1}
  lane32_swap(o0, o1);
}

// ---------------- k-loop body over [CH, END), CH/END template params -------
template <int CH, int END>
__device__ __forceinline__ void chunk_body(
    const float (&XX)[16], const float4* __restrict__ Bg, int lane,
    float4& nb0, float4& nb1, f32x16& acc0, f32x16& acc1) {
  unsigned pk0[4], pk1[4];
  pk_pair<CH, 0>(XX, pk0[0], pk1[0]);
  pk_pair<CH, 1>(XX, pk0[1], pk1[1]);
  pk_pair<CH, 2>(XX, pk0[2], pk1[2]);
  pk_pair<CH, 3>(XX, pk0[3], pk1[3]);

  // B-register selected by CHUNK PARITY (prologues must load by parity too)
  float4 bh;
  if constexpr ((CH & 1) == 0) bh = nb0; else bh = nb1;
  if constexpr (CH + 2 < END) {
    if constexpr ((CH & 1) == 0) nb0 = Bg[(CH + 2) * 64 + lane];
    else                         nb1 = Bg[(CH + 2) * 64 + lane];
  }
  short8v A0, A1, BH;
  __builtin_memcpy(&A0, pk0, 16);
  __builtin_memcpy(&A1, pk1, 16);
  __builtin_memcpy(&BH, &bh, 16);

  acc0 = __builtin_amdgcn_mfma_f32_32x32x16_bf16(A0, BH, acc0, 0, 0, 0);
  acc1 = __builtin_amdgcn_mfma_f32_32x32x16_bf16(A1, BH, acc1, 0, 0, 0);
}

template <int CH, int END>
struct LoopR {
  static __device__ __forceinline__ void run(
      const float (&XX)[16], const float4* __restrict__ Bg, int lane,
      float4& nb0, float4& nb1, f32x16& acc0, f32x16& acc1) {
    chunk_body<CH, END>(XX, Bg, lane, nb0, nb1, acc0, acc1);
    LoopR<CH + 1, END>::run(XX, Bg, lane, nb0, nb1, acc0, acc1);
  }
};
template <int END>
struct LoopR<END, END> {
  static __device__ __forceinline__ void run(
      const float (&)[16], const float4* __restrict__, int,
      float4&, float4&, f32x16&, f32x16&) {}
};

// 2-wave blocks: 128 thr. grid 4096: bb -> b = bb>>2, cg = bb&3; lane l owns
// channel cg*64 + l. Wave 0: chunks [0,31) -> dump acc to LDS; wave 1:
// chunks [31,61) -> add partials, transpose, epilogue. ONE barrier.
__global__ __launch_bounds__(128, 2) void symcon_kernel(
    const float* __restrict__ x,   // [B,C,L]
    const float* __restrict__ y,   // [B,E]
    const float* __restrict__ W3,  // [E,K3,C]
    const float* __restrict__ W2,  // [E,K2,C]
    const float* __restrict__ W1,  // [E,1,C]
    const unsigned short* __restrict__ wsFrag,
    float* __restrict__ out)       // [B,C]
{
  // sPart [64][33] f32 (8448 B), reused as sT[28][STSTR] (7616 B) by wave 1
  __shared__ __attribute__((aligned(16))) float sPart[64 * 33];
  float* sT = sPart;

  const int tid = threadIdx.x;
  const int lane = tid & 63, wid = tid >> 6;
  const int bb = blockIdx.x;
  const int b = bb >> 2;
  const int c = (bb & 3) * 64 + lane;      // this lane's channel

  // x row -> 16 registers (constant indices only); both waves load the same
  float XX[16];
  {
    const float4* xg = (const float4*)(x + ((size_t)b * C_ + c) * L_);
    #pragma unroll
    for (int i = 0; i < 4; i++) {
      float4 v = xg[i];
      XX[i * 4 + 0] = v.x; XX[i * 4 + 1] = v.y;
      XX[i * 4 + 2] = v.z; XX[i * 4 + 3] = v.w;
    }
  }

  const float4* Bg = (const float4*)wsFrag;
  f32x16 acc0 = (f32x16)0.f, acc1 = (f32x16)0.f;
  float4 nb0, nb1;

  if (wid == 0) {
    // start CH=0 (even): nb0 = chunk 0, nb1 = chunk 1
    nb0 = Bg[0 * 64 + lane];
    nb1 = Bg[1 * 64 + lane];
    LoopR<0, SPLIT>::run(XX, Bg, lane, nb0, nb1, acc0, acc1);
    // dump partials: word addr 33*lane + r -> bank (lane+r)&31, 2-way = free
    #pragma unroll
    for (int r = 0; r < 16; ++r) {
      sPart[lane * 33 + r]      = acc0[r];
      sPart[lane * 33 + 16 + r] = acc1[r];
    }
  } else {
    // start CH=31 (ODD): load BY PARITY — nb1 = chunk 31, nb0 = chunk 32.
    // (R15 bug: these two were swapped -> whole wave-1 B-stream off by one.)
    nb1 = Bg[SPLIT * 64 + lane];
    nb0 = Bg[(SPLIT + 1) * 64 + lane];
    LoopR<SPLIT, NCH2>::run(XX, Bg, lane, nb0, nb1, acc0, acc1);
  }
  __syncthreads();

  if (wid == 1) {
    // combine (same-wave DS in-order: these reads complete before sT writes)
    #pragma unroll
    for (int r = 0; r < 16; ++r) {
      acc0[r] += sPart[lane * 33 + r];
      acc1[r] += sPart[lane * 33 + 16 + r];
    }

    // D -> sT transpose (m74/m101-verified layout): lane l, reg r holds
    // t[ch = (r&3)+8*(r>>2)+4*(l>>5) (+32 for acc1)][kcol = l&31].
    const int kcol = lane & 31, hi = lane >> 5;
    if (kcol < 28) {
      #pragma unroll
      for (int q = 0; q < 4; ++q) {
        f32x4 v0, v1;
        #pragma unroll
        for (int i2 = 0; i2 < 4; ++i2) {
          v0[i2] = acc0[4 * q + i2];
          v1[i2] = acc1[4 * q + i2];
        }
        *(f32x4*)&sT[kcol * STSTR +      8 * q + 4 * hi] = v0;
        *(f32x4*)&sT[kcol * STSTR + 32 + 8 * q + 4 * hi] = v1;
      }
    }
    float t[28];
    #pragma unroll
    for (int k = 0; k < 28; ++k) t[k] = sT[k * STSTR + lane];

    // epilogue (verbatim math from verified rounds)
    float yreg[E_];
    #pragma unroll
    for (int e = 0; e < E_; e++) yreg[e] = y[b * E_ + e];

    float result = 0.f;
    #pragma unroll
    for (int k = 0; k < K3_; k++) {
      const float* w3p = &W3[k * C_ + c];
      float w3k = 0.f;
      #pragma unroll
      for (int e = 0; e < E_; e++) w3k += w3p[e * K3_ * C_] * yreg[e];
      result += t[k] * w3k;
    }
    #pragma unroll
    for (int k2 = 0; k2 < K2_; k2++) {
      const float* w2p = &W2[k2 * C_ + c];
      float w2k = 0.f;
      #pragma unroll
      for (int e = 0; e < E_; e++) w2k += w2p[e * K2_ * C_] * yreg[e];
      result += t[23 + k2] * w2k;
    }
    {
      float w1v = 0.f;
      #pragma unroll
      for (int e = 0; e < E_; e++) w1v += W1[e * C_ + c] * yreg[e];
      result += t[27] * w1v;
    }

    out[(size_t)b * C_ + c] = result;
  }
}

extern "C" void kernel_launch(void* const* d_in, const int* in_sizes, int n_in,
                              void* d_out, int out_size, void* d_ws, size_t ws_size,
                              hipStream_t stream) {
  const float* x  = (const float*)d_in[0];
  const float* y  = (const float*)d_in[1];
  const float* U3 = (const float*)d_in[2];
  const float* U2 = (const float*)d_in[3];
  const float* U1 = (const float*)d_in[4];
  const float* W3 = (const float*)d_in[5];
  const float* W2 = (const float*)d_in[6];
  const float* W1 = (const float*)d_in[7];
  float* out = (float*)d_out;

  unsigned short* wsFrag = (unsigned short*)d_ws;  // 61*64*8 u16 = 62464 B

  prep_kernel<<<dim3(NCH2), dim3(64), 0, stream>>>(U3, U2, U1, wsFrag);
  symcon_kernel<<<dim3(B_ * 4), dim3(128), 0, stream>>>(
      x, y, W3, W2, W1, wsFrag, out);
}